// Round 1
// baseline (5878.870 us; speedup 1.0000x reference)
//
#include <hip/hip_runtime.h>

// AtomSelectionModel: GINE-style GNN, fp32.
//   x = relu([x_upd | Zc[g] | Zb[g]] @ W_emb + b_emb)
//   4x: agg = scatter_sum(relu(x[src] + relu(attr@We+be)), dst)
//       h = relu((x+agg)@W1+b1); x = x + relu(h@W2+b2)
//   logit = relu([x | x_inp]@Wm1+bm1)@Wm2+bm2 ; P = segment_softmax(logit, n2g)
//
// GEMM skeleton: 256 thr/block, 64 rows x 128 cols, K chunked by 32.
//  - W chunk in LDS with skew swizzle SWZ (breaks the cg/cg+4 4-way pattern -> 2-way, free)
//  - input chunk staged TRANSPOSED [k][row] so compute reads are ds_read_b128
//  - thread owns 4 rows x 8 cols = 32 fp32 acc; per k: 3 b128 LDS reads + 32 FMA (VALU-bound)

#define V_N 262144
#define E_N 524288
#define N_G 8192
#define FV_D 64
#define H_D 128

#define WSTRIDE 140   // 32-row W tile, swizzled row; 140*4B % 16 == 0
#define ISTRIDE 68    // transposed input tile row; 68*4B % 16 == 0
#define SWZ(c) ((c) + (((c) >> 5) << 2))

__device__ __forceinline__ void stage_in4(float* in_ldsT, int kk, int r, float4 v)
{
  in_ldsT[(kk + 0) * ISTRIDE + r] = v.x;
  in_ldsT[(kk + 1) * ISTRIDE + r] = v.y;
  in_ldsT[(kk + 2) * ISTRIDE + r] = v.z;
  in_ldsT[(kk + 3) * ISTRIDE + r] = v.w;
}

__device__ __forceinline__ void mma32(const float* in_ldsT, const float* w_lds,
                                      int r0, int swc0, int swc1, float acc[4][8])
{
  #pragma unroll 4
  for (int kk = 0; kk < 32; ++kk) {
    const float4 a  = *(const float4*)&in_ldsT[kk * ISTRIDE + r0];
    const float4 w0 = *(const float4*)&w_lds[kk * WSTRIDE + swc0];
    const float4 w1 = *(const float4*)&w_lds[kk * WSTRIDE + swc1];
    const float av[4] = {a.x, a.y, a.z, a.w};
    const float wv[8] = {w0.x, w0.y, w0.z, w0.w, w1.x, w1.y, w1.z, w1.w};
    #pragma unroll
    for (int i = 0; i < 4; ++i)
      #pragma unroll
      for (int j = 0; j < 8; ++j)
        acc[i][j] = fmaf(av[i], wv[j], acc[i][j]);
  }
}

// ---------------- embed: x = relu([x_upd | Zc[g] | Zb[g]] @ W + b), K=384 ----
__global__ __launch_bounds__(256, 4) void k_embed(
    const float* __restrict__ x_upd, const float* __restrict__ Zc,
    const float* __restrict__ Zb, const int* __restrict__ n2g,
    const float* __restrict__ W, const float* __restrict__ bias,
    float* __restrict__ xout)
{
  __shared__ float w_lds[32 * WSTRIDE];
  __shared__ float in_ldsT[32 * ISTRIDE];
  __shared__ int g_lds[64];
  const int t = threadIdx.x;
  const int row0 = blockIdx.x * 64;
  if (t < 64) g_lds[t] = n2g[row0 + t];
  const int r0 = (t >> 4) << 2;
  const int c0 = (t & 15) * 8;
  const int swc0 = SWZ(c0), swc1 = SWZ(c0 + 4);
  const int rs = t >> 2, qs = t & 3;
  const int kw = t >> 3, cw = (t & 7) * 16;
  float acc[4][8] = {};
  __syncthreads();                       // g_lds visible
  for (int kc = 0; kc < 12; ++kc) {
    const int k0 = kc * 32;
    const float* src;
    if (k0 < 128)      src = x_upd + (size_t)(row0 + rs) * H_D + k0;
    else if (k0 < 256) src = Zc + (size_t)g_lds[rs] * H_D + (k0 - 128);
    else               src = Zb + (size_t)g_lds[rs] * H_D + (k0 - 256);
    const float4 v0 = *(const float4*)(src + qs * 4);
    const float4 v1 = *(const float4*)(src + 16 + qs * 4);
    const float* wp = W + (size_t)(k0 + kw) * H_D + cw;
    float4 wv[4];
    #pragma unroll
    for (int u = 0; u < 4; ++u) wv[u] = *(const float4*)(wp + u * 4);
    __syncthreads();                     // previous compute done
    #pragma unroll
    for (int u = 0; u < 4; ++u)
      *(float4*)&w_lds[kw * WSTRIDE + SWZ(cw + u * 4)] = wv[u];
    stage_in4(in_ldsT, qs * 4, rs, v0);
    stage_in4(in_ldsT, qs * 4 + 16, rs, v1);
    __syncthreads();
    mma32(in_ldsT, w_lds, r0, swc0, swc1, acc);
  }
  const float4 b0v = *(const float4*)(bias + c0);
  const float4 b1v = *(const float4*)(bias + c0 + 4);
  const float bv[8] = {b0v.x, b0v.y, b0v.z, b0v.w, b1v.x, b1v.y, b1v.z, b1v.w};
  #pragma unroll
  for (int i = 0; i < 4; ++i) {
    float4 o0, o1;
    o0.x = fmaxf(acc[i][0] + bv[0], 0.f); o0.y = fmaxf(acc[i][1] + bv[1], 0.f);
    o0.z = fmaxf(acc[i][2] + bv[2], 0.f); o0.w = fmaxf(acc[i][3] + bv[3], 0.f);
    o1.x = fmaxf(acc[i][4] + bv[4], 0.f); o1.y = fmaxf(acc[i][5] + bv[5], 0.f);
    o1.z = fmaxf(acc[i][6] + bv[6], 0.f); o1.w = fmaxf(acc[i][7] + bv[7], 0.f);
    float* op = xout + (size_t)(row0 + r0 + i) * H_D;
    *(float4*)(op + c0) = o0;
    *(float4*)(op + c0 + 4) = o1;
  }
}

// ---------------- layer GEMM1: h = relu((x+agg) @ W + b), K=128 -------------
__global__ __launch_bounds__(256, 4) void k_gemm_xa(
    const float* __restrict__ x, const float* __restrict__ agg,
    const float* __restrict__ W, const float* __restrict__ bias,
    float* __restrict__ hout)
{
  __shared__ float w_lds[32 * WSTRIDE];
  __shared__ float in_ldsT[32 * ISTRIDE];
  const int t = threadIdx.x;
  const int row0 = blockIdx.x * 64;
  const int r0 = (t >> 4) << 2;
  const int c0 = (t & 15) * 8;
  const int swc0 = SWZ(c0), swc1 = SWZ(c0 + 4);
  const int rs = t >> 2, qs = t & 3;
  const int kw = t >> 3, cw = (t & 7) * 16;
  float acc[4][8] = {};
  for (int kc = 0; kc < 4; ++kc) {
    const int k0 = kc * 32;
    const float* px = x   + (size_t)(row0 + rs) * H_D + k0;
    const float* pa = agg + (size_t)(row0 + rs) * H_D + k0;
    float4 v0 = *(const float4*)(px + qs * 4);
    float4 v1 = *(const float4*)(px + 16 + qs * 4);
    const float4 a0 = *(const float4*)(pa + qs * 4);
    const float4 a1 = *(const float4*)(pa + 16 + qs * 4);
    v0.x += a0.x; v0.y += a0.y; v0.z += a0.z; v0.w += a0.w;
    v1.x += a1.x; v1.y += a1.y; v1.z += a1.z; v1.w += a1.w;
    const float* wp = W + (size_t)(k0 + kw) * H_D + cw;
    float4 wv[4];
    #pragma unroll
    for (int u = 0; u < 4; ++u) wv[u] = *(const float4*)(wp + u * 4);
    __syncthreads();
    #pragma unroll
    for (int u = 0; u < 4; ++u)
      *(float4*)&w_lds[kw * WSTRIDE + SWZ(cw + u * 4)] = wv[u];
    stage_in4(in_ldsT, qs * 4, rs, v0);
    stage_in4(in_ldsT, qs * 4 + 16, rs, v1);
    __syncthreads();
    mma32(in_ldsT, w_lds, r0, swc0, swc1, acc);
  }
  const float4 b0v = *(const float4*)(bias + c0);
  const float4 b1v = *(const float4*)(bias + c0 + 4);
  const float bv[8] = {b0v.x, b0v.y, b0v.z, b0v.w, b1v.x, b1v.y, b1v.z, b1v.w};
  #pragma unroll
  for (int i = 0; i < 4; ++i) {
    float4 o0, o1;
    o0.x = fmaxf(acc[i][0] + bv[0], 0.f); o0.y = fmaxf(acc[i][1] + bv[1], 0.f);
    o0.z = fmaxf(acc[i][2] + bv[2], 0.f); o0.w = fmaxf(acc[i][3] + bv[3], 0.f);
    o1.x = fmaxf(acc[i][4] + bv[4], 0.f); o1.y = fmaxf(acc[i][5] + bv[5], 0.f);
    o1.z = fmaxf(acc[i][6] + bv[6], 0.f); o1.w = fmaxf(acc[i][7] + bv[7], 0.f);
    float* op = hout + (size_t)(row0 + r0 + i) * H_D;
    *(float4*)(op + c0) = o0;
    *(float4*)(op + c0 + 4) = o1;
  }
}

// ---------------- layer GEMM2: x += relu(h @ W + b), K=128 ------------------
__global__ __launch_bounds__(256, 4) void k_gemm_res(
    const float* __restrict__ h, const float* __restrict__ W,
    const float* __restrict__ bias, float* __restrict__ x)
{
  __shared__ float w_lds[32 * WSTRIDE];
  __shared__ float in_ldsT[32 * ISTRIDE];
  const int t = threadIdx.x;
  const int row0 = blockIdx.x * 64;
  const int r0 = (t >> 4) << 2;
  const int c0 = (t & 15) * 8;
  const int swc0 = SWZ(c0), swc1 = SWZ(c0 + 4);
  const int rs = t >> 2, qs = t & 3;
  const int kw = t >> 3, cw = (t & 7) * 16;
  float acc[4][8] = {};
  for (int kc = 0; kc < 4; ++kc) {
    const int k0 = kc * 32;
    const float* ph = h + (size_t)(row0 + rs) * H_D + k0;
    const float4 v0 = *(const float4*)(ph + qs * 4);
    const float4 v1 = *(const float4*)(ph + 16 + qs * 4);
    const float* wp = W + (size_t)(k0 + kw) * H_D + cw;
    float4 wv[4];
    #pragma unroll
    for (int u = 0; u < 4; ++u) wv[u] = *(const float4*)(wp + u * 4);
    __syncthreads();
    #pragma unroll
    for (int u = 0; u < 4; ++u)
      *(float4*)&w_lds[kw * WSTRIDE + SWZ(cw + u * 4)] = wv[u];
    stage_in4(in_ldsT, qs * 4, rs, v0);
    stage_in4(in_ldsT, qs * 4 + 16, rs, v1);
    __syncthreads();
    mma32(in_ldsT, w_lds, r0, swc0, swc1, acc);
  }
  const float4 b0v = *(const float4*)(bias + c0);
  const float4 b1v = *(const float4*)(bias + c0 + 4);
  const float bv[8] = {b0v.x, b0v.y, b0v.z, b0v.w, b1v.x, b1v.y, b1v.z, b1v.w};
  #pragma unroll
  for (int i = 0; i < 4; ++i) {
    float* xp = x + (size_t)(row0 + r0 + i) * H_D;
    float4 x0 = *(const float4*)(xp + c0);
    float4 x1 = *(const float4*)(xp + c0 + 4);
    x0.x += fmaxf(acc[i][0] + bv[0], 0.f); x0.y += fmaxf(acc[i][1] + bv[1], 0.f);
    x0.z += fmaxf(acc[i][2] + bv[2], 0.f); x0.w += fmaxf(acc[i][3] + bv[3], 0.f);
    x1.x += fmaxf(acc[i][4] + bv[4], 0.f); x1.y += fmaxf(acc[i][5] + bv[5], 0.f);
    x1.z += fmaxf(acc[i][6] + bv[6], 0.f); x1.w += fmaxf(acc[i][7] + bv[7], 0.f);
    *(float4*)(xp + c0) = x0;
    *(float4*)(xp + c0 + 4) = x1;
  }
}

// ---- scatter: agg[dst] += relu(x[src] + relu(attr@We+be)), e recomputed ----
__global__ __launch_bounds__(256, 4) void k_scatter(
    const float* __restrict__ x, const float* __restrict__ attr,
    const int* __restrict__ eidx, const float* __restrict__ We,
    const float* __restrict__ be, float* __restrict__ agg)
{
  __shared__ float w_lds[16 * WSTRIDE];
  __shared__ float a_lds[128];
  const int t = threadIdx.x;
  const int e0 = blockIdx.x * 8;
  {
    const int kk = t >> 4, c = (t & 15) * 8;
    const float4 w0 = *(const float4*)(We + kk * H_D + c);
    const float4 w1 = *(const float4*)(We + kk * H_D + c + 4);
    *(float4*)&w_lds[kk * WSTRIDE + SWZ(c)]     = w0;
    *(float4*)&w_lds[kk * WSTRIDE + SWZ(c + 4)] = w1;
  }
  if (t < 128) a_lds[t] = attr[(size_t)e0 * 16 + t];
  __syncthreads();
  const int el = t >> 5, c = (t & 31) * 4;
  const int edge = e0 + el;
  const int src = eidx[edge];
  const int dst = eidx[E_N + edge];
  float4 acc = *(const float4*)(be + c);
  const int swc = SWZ(c);
  #pragma unroll
  for (int k = 0; k < 16; ++k) {
    const float av = a_lds[el * 16 + k];
    const float4 w = *(const float4*)&w_lds[k * WSTRIDE + swc];
    acc.x = fmaf(av, w.x, acc.x);
    acc.y = fmaf(av, w.y, acc.y);
    acc.z = fmaf(av, w.z, acc.z);
    acc.w = fmaf(av, w.w, acc.w);
  }
  const float4 xv = *(const float4*)(x + (size_t)src * H_D + c);
  float4 m;
  m.x = fmaxf(xv.x + fmaxf(acc.x, 0.f), 0.f);
  m.y = fmaxf(xv.y + fmaxf(acc.y, 0.f), 0.f);
  m.z = fmaxf(xv.z + fmaxf(acc.z, 0.f), 0.f);
  m.w = fmaxf(xv.w + fmaxf(acc.w, 0.f), 0.f);
  float* ap = agg + (size_t)dst * H_D + c;
  unsafeAtomicAdd(ap + 0, m.x);
  unsafeAtomicAdd(ap + 1, m.y);
  unsafeAtomicAdd(ap + 2, m.z);
  unsafeAtomicAdd(ap + 3, m.w);
}

// ---- head: logit = relu([x | x_inp]@Wm1+bm1)@Wm2+bm2, K=192 ----------------
__global__ __launch_bounds__(256, 4) void k_head(
    const float* __restrict__ x, const float* __restrict__ x_inp,
    const float* __restrict__ Wm1, const float* __restrict__ bm1,
    const float* __restrict__ Wm2, const float* __restrict__ bm2,
    float* __restrict__ logit)
{
  __shared__ float w_lds[32 * WSTRIDE];
  __shared__ float in_ldsT[32 * ISTRIDE];
  const int t = threadIdx.x;
  const int row0 = blockIdx.x * 64;
  const int r0 = (t >> 4) << 2;
  const int c0 = (t & 15) * 8;
  const int swc0 = SWZ(c0), swc1 = SWZ(c0 + 4);
  const int rs = t >> 2, qs = t & 3;
  const int kw = t >> 3, cw = (t & 7) * 16;
  float acc[4][8] = {};
  for (int kc = 0; kc < 6; ++kc) {
    const int k0 = kc * 32;
    const float* src = (k0 < 128)
        ? x + (size_t)(row0 + rs) * H_D + k0
        : x_inp + (size_t)(row0 + rs) * FV_D + (k0 - 128);
    const float4 v0 = *(const float4*)(src + qs * 4);
    const float4 v1 = *(const float4*)(src + 16 + qs * 4);
    const float* wp = Wm1 + (size_t)(k0 + kw) * H_D + cw;
    float4 wv[4];
    #pragma unroll
    for (int u = 0; u < 4; ++u) wv[u] = *(const float4*)(wp + u * 4);
    __syncthreads();
    #pragma unroll
    for (int u = 0; u < 4; ++u)
      *(float4*)&w_lds[kw * WSTRIDE + SWZ(cw + u * 4)] = wv[u];
    stage_in4(in_ldsT, qs * 4, rs, v0);
    stage_in4(in_ldsT, qs * 4 + 16, rs, v1);
    __syncthreads();
    mma32(in_ldsT, w_lds, r0, swc0, swc1, acc);
  }
  const float4 b0v = *(const float4*)(bm1 + c0);
  const float4 b1v = *(const float4*)(bm1 + c0 + 4);
  const float4 w0v = *(const float4*)(Wm2 + c0);
  const float4 w1v = *(const float4*)(Wm2 + c0 + 4);
  const float bv[8] = {b0v.x, b0v.y, b0v.z, b0v.w, b1v.x, b1v.y, b1v.z, b1v.w};
  const float wv[8] = {w0v.x, w0v.y, w0v.z, w0v.w, w1v.x, w1v.y, w1v.z, w1v.w};
  float s[4];
  #pragma unroll
  for (int i = 0; i < 4; ++i) {
    float v = 0.f;
    #pragma unroll
    for (int j = 0; j < 8; ++j)
      v += fmaxf(acc[i][j] + bv[j], 0.f) * wv[j];
    s[i] = v;
  }
  #pragma unroll
  for (int off = 1; off < 16; off <<= 1) {
    #pragma unroll
    for (int i = 0; i < 4; ++i) s[i] += __shfl_xor(s[i], off);
  }
  if ((t & 15) == 0) {
    const float bb = bm2[0];
    #pragma unroll
    for (int i = 0; i < 4; ++i) logit[row0 + r0 + i] = s[i] + bb;
  }
}

// ---- segment softmax over sorted n2g: one wave per graph -------------------
__device__ __forceinline__ int lower_bound_i(const int* __restrict__ a, int n, int v)
{
  int lo = 0, hi = n;
  while (lo < hi) {
    const int mid = (lo + hi) >> 1;
    if (a[mid] < v) lo = mid + 1; else hi = mid;
  }
  return lo;
}

__global__ __launch_bounds__(256, 4) void k_softmax(
    const float* __restrict__ logit, const int* __restrict__ n2g,
    float* __restrict__ P)
{
  const int lane = threadIdx.x & 63;
  const int g = blockIdx.x * 4 + (threadIdx.x >> 6);
  const int s = lower_bound_i(n2g, V_N, g);
  const int e = lower_bound_i(n2g, V_N, g + 1);
  float m = -3.4e38f;
  for (int i = s + lane; i < e; i += 64) m = fmaxf(m, logit[i]);
  #pragma unroll
  for (int off = 32; off; off >>= 1) m = fmaxf(m, __shfl_xor(m, off));
  float sum = 0.f;
  for (int i = s + lane; i < e; i += 64) sum += __expf(logit[i] - m);
  #pragma unroll
  for (int off = 32; off; off >>= 1) sum += __shfl_xor(sum, off);
  const float inv = 1.f / sum;
  for (int i = s + lane; i < e; i += 64) P[i] = __expf(logit[i] - m) * inv;
}

extern "C" void kernel_launch(void* const* d_in, const int* in_sizes, int n_in,
                              void* d_out, int out_size, void* d_ws, size_t ws_size,
                              hipStream_t stream)
{
  const float* x_inp  = (const float*)d_in[0];
  const int*   eidx   = (const int*)  d_in[1];
  const float* attr   = (const float*)d_in[2];
  const float* x_upd  = (const float*)d_in[3];
  const float* Zc     = (const float*)d_in[4];
  const float* Zb     = (const float*)d_in[5];
  const int*   n2g    = (const int*)  d_in[6];
  const float* W_emb  = (const float*)d_in[7];
  const float* b_emb  = (const float*)d_in[8];
  const float* W_edge = (const float*)d_in[9];
  const float* b_edge = (const float*)d_in[10];
  const float* W1     = (const float*)d_in[11];
  const float* b1     = (const float*)d_in[12];
  const float* W2     = (const float*)d_in[13];
  const float* b2     = (const float*)d_in[14];
  const float* W_m1   = (const float*)d_in[15];
  const float* b_m1   = (const float*)d_in[16];
  const float* W_m2   = (const float*)d_in[17];
  const float* b_m2   = (const float*)d_in[18];

  float* ws    = (float*)d_ws;
  float* x     = ws;                          // V*H
  float* agg   = x + (size_t)V_N * H_D;       // V*H  (also reused as h: safe,
                                              //  each block reads its own rows
                                              //  before its epilogue writes them)
  float* logit = agg + (size_t)V_N * H_D;     // V

  k_embed<<<V_N / 64, 256, 0, stream>>>(x_upd, Zc, Zb, n2g, W_emb, b_emb, x);
  for (int l = 0; l < 4; ++l) {
    hipMemsetAsync(agg, 0, (size_t)V_N * H_D * sizeof(float), stream);
    k_scatter<<<E_N / 8, 256, 0, stream>>>(x, attr, eidx, W_edge, b_edge, agg);
    k_gemm_xa<<<V_N / 64, 256, 0, stream>>>(x, agg, W1 + (size_t)l * H_D * H_D,
                                            b1 + (size_t)l * H_D, agg /* h */);
    k_gemm_res<<<V_N / 64, 256, 0, stream>>>(agg /* h */, W2 + (size_t)l * H_D * H_D,
                                             b2 + (size_t)l * H_D, x);
  }
  k_head<<<V_N / 64, 256, 0, stream>>>(x, x_inp, W_m1, b_m1, W_m2, b_m2, logit);
  k_softmax<<<N_G / 4, 256, 0, stream>>>(logit, n2g, (float*)d_out);
}

// Round 2
// 3262.766 us; speedup vs baseline: 1.8018x; 1.8018x over previous
//
#include <hip/hip_runtime.h>

// AtomSelectionModel: GINE-style GNN, fp32.
// R2: scatter+fp32 atomics (890us x4, atomic-bound, 8x write amplification)
//     replaced by once-per-call CSR-by-dst build + per-node gather.

#define V_N 262144
#define E_N 524288
#define N_G 8192
#define FV_D 64
#define H_D 128

#define WSTRIDE 140   // 32-row W tile, swizzled row; 140*4B % 16 == 0
#define ISTRIDE 68    // transposed input tile row; 68*4B % 16 == 0
#define SWZ(c) ((c) + (((c) >> 5) << 2))

__device__ __forceinline__ void stage_in4(float* in_ldsT, int kk, int r, float4 v)
{
  in_ldsT[(kk + 0) * ISTRIDE + r] = v.x;
  in_ldsT[(kk + 1) * ISTRIDE + r] = v.y;
  in_ldsT[(kk + 2) * ISTRIDE + r] = v.z;
  in_ldsT[(kk + 3) * ISTRIDE + r] = v.w;
}

__device__ __forceinline__ void mma32(const float* in_ldsT, const float* w_lds,
                                      int r0, int swc0, int swc1, float acc[4][8])
{
  #pragma unroll 4
  for (int kk = 0; kk < 32; ++kk) {
    const float4 a  = *(const float4*)&in_ldsT[kk * ISTRIDE + r0];
    const float4 w0 = *(const float4*)&w_lds[kk * WSTRIDE + swc0];
    const float4 w1 = *(const float4*)&w_lds[kk * WSTRIDE + swc1];
    const float av[4] = {a.x, a.y, a.z, a.w};
    const float wv[8] = {w0.x, w0.y, w0.z, w0.w, w1.x, w1.y, w1.z, w1.w};
    #pragma unroll
    for (int i = 0; i < 4; ++i)
      #pragma unroll
      for (int j = 0; j < 8; ++j)
        acc[i][j] = fmaf(av[i], wv[j], acc[i][j]);
  }
}

// ---------------- embed: x = relu([x_upd | Zc[g] | Zb[g]] @ W + b), K=384 ----
__global__ __launch_bounds__(256, 4) void k_embed(
    const float* __restrict__ x_upd, const float* __restrict__ Zc,
    const float* __restrict__ Zb, const int* __restrict__ n2g,
    const float* __restrict__ W, const float* __restrict__ bias,
    float* __restrict__ xout)
{
  __shared__ float w_lds[32 * WSTRIDE];
  __shared__ float in_ldsT[32 * ISTRIDE];
  __shared__ int g_lds[64];
  const int t = threadIdx.x;
  const int row0 = blockIdx.x * 64;
  if (t < 64) g_lds[t] = n2g[row0 + t];
  const int r0 = (t >> 4) << 2;
  const int c0 = (t & 15) * 8;
  const int swc0 = SWZ(c0), swc1 = SWZ(c0 + 4);
  const int rs = t >> 2, qs = t & 3;
  const int kw = t >> 3, cw = (t & 7) * 16;
  float acc[4][8] = {};
  __syncthreads();                       // g_lds visible
  for (int kc = 0; kc < 12; ++kc) {
    const int k0 = kc * 32;
    const float* src;
    if (k0 < 128)      src = x_upd + (size_t)(row0 + rs) * H_D + k0;
    else if (k0 < 256) src = Zc + (size_t)g_lds[rs] * H_D + (k0 - 128);
    else               src = Zb + (size_t)g_lds[rs] * H_D + (k0 - 256);
    const float4 v0 = *(const float4*)(src + qs * 4);
    const float4 v1 = *(const float4*)(src + 16 + qs * 4);
    const float* wp = W + (size_t)(k0 + kw) * H_D + cw;
    float4 wv[4];
    #pragma unroll
    for (int u = 0; u < 4; ++u) wv[u] = *(const float4*)(wp + u * 4);
    __syncthreads();                     // previous compute done
    #pragma unroll
    for (int u = 0; u < 4; ++u)
      *(float4*)&w_lds[kw * WSTRIDE + SWZ(cw + u * 4)] = wv[u];
    stage_in4(in_ldsT, qs * 4, rs, v0);
    stage_in4(in_ldsT, qs * 4 + 16, rs, v1);
    __syncthreads();
    mma32(in_ldsT, w_lds, r0, swc0, swc1, acc);
  }
  const float4 b0v = *(const float4*)(bias + c0);
  const float4 b1v = *(const float4*)(bias + c0 + 4);
  const float bv[8] = {b0v.x, b0v.y, b0v.z, b0v.w, b1v.x, b1v.y, b1v.z, b1v.w};
  #pragma unroll
  for (int i = 0; i < 4; ++i) {
    float4 o0, o1;
    o0.x = fmaxf(acc[i][0] + bv[0], 0.f); o0.y = fmaxf(acc[i][1] + bv[1], 0.f);
    o0.z = fmaxf(acc[i][2] + bv[2], 0.f); o0.w = fmaxf(acc[i][3] + bv[3], 0.f);
    o1.x = fmaxf(acc[i][4] + bv[4], 0.f); o1.y = fmaxf(acc[i][5] + bv[5], 0.f);
    o1.z = fmaxf(acc[i][6] + bv[6], 0.f); o1.w = fmaxf(acc[i][7] + bv[7], 0.f);
    float* op = xout + (size_t)(row0 + r0 + i) * H_D;
    *(float4*)(op + c0) = o0;
    *(float4*)(op + c0 + 4) = o1;
  }
}

// ---------------- layer GEMM1: h = relu((x+agg) @ W + b), K=128 -------------
__global__ __launch_bounds__(256, 4) void k_gemm_xa(
    const float* __restrict__ x, const float* __restrict__ agg,
    const float* __restrict__ W, const float* __restrict__ bias,
    float* __restrict__ hout)
{
  __shared__ float w_lds[32 * WSTRIDE];
  __shared__ float in_ldsT[32 * ISTRIDE];
  const int t = threadIdx.x;
  const int row0 = blockIdx.x * 64;
  const int r0 = (t >> 4) << 2;
  const int c0 = (t & 15) * 8;
  const int swc0 = SWZ(c0), swc1 = SWZ(c0 + 4);
  const int rs = t >> 2, qs = t & 3;
  const int kw = t >> 3, cw = (t & 7) * 16;
  float acc[4][8] = {};
  for (int kc = 0; kc < 4; ++kc) {
    const int k0 = kc * 32;
    const float* px = x   + (size_t)(row0 + rs) * H_D + k0;
    const float* pa = agg + (size_t)(row0 + rs) * H_D + k0;
    float4 v0 = *(const float4*)(px + qs * 4);
    float4 v1 = *(const float4*)(px + 16 + qs * 4);
    const float4 a0 = *(const float4*)(pa + qs * 4);
    const float4 a1 = *(const float4*)(pa + 16 + qs * 4);
    v0.x += a0.x; v0.y += a0.y; v0.z += a0.z; v0.w += a0.w;
    v1.x += a1.x; v1.y += a1.y; v1.z += a1.z; v1.w += a1.w;
    const float* wp = W + (size_t)(k0 + kw) * H_D + cw;
    float4 wv[4];
    #pragma unroll
    for (int u = 0; u < 4; ++u) wv[u] = *(const float4*)(wp + u * 4);
    __syncthreads();
    #pragma unroll
    for (int u = 0; u < 4; ++u)
      *(float4*)&w_lds[kw * WSTRIDE + SWZ(cw + u * 4)] = wv[u];
    stage_in4(in_ldsT, qs * 4, rs, v0);
    stage_in4(in_ldsT, qs * 4 + 16, rs, v1);
    __syncthreads();
    mma32(in_ldsT, w_lds, r0, swc0, swc1, acc);
  }
  const float4 b0v = *(const float4*)(bias + c0);
  const float4 b1v = *(const float4*)(bias + c0 + 4);
  const float bv[8] = {b0v.x, b0v.y, b0v.z, b0v.w, b1v.x, b1v.y, b1v.z, b1v.w};
  #pragma unroll
  for (int i = 0; i < 4; ++i) {
    float4 o0, o1;
    o0.x = fmaxf(acc[i][0] + bv[0], 0.f); o0.y = fmaxf(acc[i][1] + bv[1], 0.f);
    o0.z = fmaxf(acc[i][2] + bv[2], 0.f); o0.w = fmaxf(acc[i][3] + bv[3], 0.f);
    o1.x = fmaxf(acc[i][4] + bv[4], 0.f); o1.y = fmaxf(acc[i][5] + bv[5], 0.f);
    o1.z = fmaxf(acc[i][6] + bv[6], 0.f); o1.w = fmaxf(acc[i][7] + bv[7], 0.f);
    float* op = hout + (size_t)(row0 + r0 + i) * H_D;
    *(float4*)(op + c0) = o0;
    *(float4*)(op + c0 + 4) = o1;
  }
}

// ---------------- layer GEMM2: x += relu(h @ W + b), K=128 ------------------
__global__ __launch_bounds__(256, 4) void k_gemm_res(
    const float* __restrict__ h, const float* __restrict__ W,
    const float* __restrict__ bias, float* __restrict__ x)
{
  __shared__ float w_lds[32 * WSTRIDE];
  __shared__ float in_ldsT[32 * ISTRIDE];
  const int t = threadIdx.x;
  const int row0 = blockIdx.x * 64;
  const int r0 = (t >> 4) << 2;
  const int c0 = (t & 15) * 8;
  const int swc0 = SWZ(c0), swc1 = SWZ(c0 + 4);
  const int rs = t >> 2, qs = t & 3;
  const int kw = t >> 3, cw = (t & 7) * 16;
  float acc[4][8] = {};
  for (int kc = 0; kc < 4; ++kc) {
    const int k0 = kc * 32;
    const float* ph = h + (size_t)(row0 + rs) * H_D + k0;
    const float4 v0 = *(const float4*)(ph + qs * 4);
    const float4 v1 = *(const float4*)(ph + 16 + qs * 4);
    const float* wp = W + (size_t)(k0 + kw) * H_D + cw;
    float4 wv[4];
    #pragma unroll
    for (int u = 0; u < 4; ++u) wv[u] = *(const float4*)(wp + u * 4);
    __syncthreads();
    #pragma unroll
    for (int u = 0; u < 4; ++u)
      *(float4*)&w_lds[kw * WSTRIDE + SWZ(cw + u * 4)] = wv[u];
    stage_in4(in_ldsT, qs * 4, rs, v0);
    stage_in4(in_ldsT, qs * 4 + 16, rs, v1);
    __syncthreads();
    mma32(in_ldsT, w_lds, r0, swc0, swc1, acc);
  }
  const float4 b0v = *(const float4*)(bias + c0);
  const float4 b1v = *(const float4*)(bias + c0 + 4);
  const float bv[8] = {b0v.x, b0v.y, b0v.z, b0v.w, b1v.x, b1v.y, b1v.z, b1v.w};
  #pragma unroll
  for (int i = 0; i < 4; ++i) {
    float* xp = x + (size_t)(row0 + r0 + i) * H_D;
    float4 x0 = *(const float4*)(xp + c0);
    float4 x1 = *(const float4*)(xp + c0 + 4);
    x0.x += fmaxf(acc[i][0] + bv[0], 0.f); x0.y += fmaxf(acc[i][1] + bv[1], 0.f);
    x0.z += fmaxf(acc[i][2] + bv[2], 0.f); x0.w += fmaxf(acc[i][3] + bv[3], 0.f);
    x1.x += fmaxf(acc[i][4] + bv[4], 0.f); x1.y += fmaxf(acc[i][5] + bv[5], 0.f);
    x1.z += fmaxf(acc[i][6] + bv[6], 0.f); x1.w += fmaxf(acc[i][7] + bv[7], 0.f);
    *(float4*)(xp + c0) = x0;
    *(float4*)(xp + c0 + 4) = x1;
  }
}

// =================== CSR build (once per call) ==============================
__global__ __launch_bounds__(256) void k_hist(const int* __restrict__ eidx,
                                              int* __restrict__ deg)
{
  const int e = blockIdx.x * 256 + threadIdx.x;
  atomicAdd(&deg[eidx[E_N + e]], 1);
}

// 256 blocks x 1024 elems: chunk-local exclusive scan + block totals
__global__ __launch_bounds__(256) void k_scan_local(const int* __restrict__ deg,
                                                    int* __restrict__ rp,
                                                    int* __restrict__ bsum)
{
  __shared__ int sc[256];
  const int t = threadIdx.x;
  const int base = blockIdx.x * 1024 + t * 4;
  const int4 d = *(const int4*)(deg + base);
  const int s4 = d.x + d.y + d.z + d.w;
  sc[t] = s4;
  __syncthreads();
  for (int off = 1; off < 256; off <<= 1) {
    int v = 0;
    if (t >= off) v = sc[t - off];
    __syncthreads();
    if (t >= off) sc[t] += v;
    __syncthreads();
  }
  const int excl = sc[t] - s4;
  int4 o;
  o.x = excl;
  o.y = excl + d.x;
  o.z = excl + d.x + d.y;
  o.w = excl + d.x + d.y + d.z;
  *(int4*)(rp + base) = o;
  if (t == 255) bsum[blockIdx.x] = sc[255];
}

__global__ __launch_bounds__(256) void k_scan_bsum(int* __restrict__ bsum)
{
  __shared__ int sc[256];
  const int t = threadIdx.x;
  const int b = bsum[t];
  sc[t] = b;
  __syncthreads();
  for (int off = 1; off < 256; off <<= 1) {
    int v = 0;
    if (t >= off) v = sc[t - off];
    __syncthreads();
    if (t >= off) sc[t] += v;
    __syncthreads();
  }
  bsum[t] = sc[t] - b;   // exclusive
}

__global__ __launch_bounds__(256) void k_scan_add(int* __restrict__ rp,
                                                  int* __restrict__ cursor,
                                                  const int* __restrict__ bsum)
{
  const int base = blockIdx.x * 1024 + threadIdx.x * 4;
  const int off = bsum[blockIdx.x];
  int4 r = *(const int4*)(rp + base);
  r.x += off; r.y += off; r.z += off; r.w += off;
  *(int4*)(rp + base) = r;
  *(int4*)(cursor + base) = r;
}

__global__ __launch_bounds__(256) void k_fill(const int* __restrict__ eidx,
                                              int* __restrict__ cursor,
                                              int* __restrict__ cs_src,
                                              int* __restrict__ cs_eid)
{
  const int e = blockIdx.x * 256 + threadIdx.x;
  const int d = eidx[E_N + e];
  const int p = atomicAdd(&cursor[d], 1);
  cs_src[p] = eidx[e];
  cs_eid[p] = e;
}

// ---- gather: agg[v] = sum_{e: dst=v} relu(x[src_e] + relu(attr_e@We+be)) ---
// half-wave (32 lanes x float4) per node; We staged in LDS; no atomics.
__global__ __launch_bounds__(256, 4) void k_gather(
    const float* __restrict__ x, const float* __restrict__ attr,
    const int* __restrict__ rp, const int* __restrict__ deg,
    const int* __restrict__ cs_src, const int* __restrict__ cs_eid,
    const float* __restrict__ We, const float* __restrict__ be,
    float* __restrict__ agg)
{
  __shared__ float we_lds[16 * 128];
  const int t = threadIdx.x;
  {
    const int kk = t >> 4, c = (t & 15) * 8;
    *(float4*)&we_lds[kk * 128 + c]     = *(const float4*)(We + kk * H_D + c);
    *(float4*)&we_lds[kk * 128 + c + 4] = *(const float4*)(We + kk * H_D + c + 4);
  }
  __syncthreads();
  const int slot = t >> 5;
  const int c0 = (t & 31) * 4;
  const int v = blockIdx.x * 8 + slot;
  const int start = rp[v];
  const int n = deg[v];
  const float4 bev = *(const float4*)(be + c0);
  float4 acc = {0.f, 0.f, 0.f, 0.f};
  for (int i = 0; i < n; ++i) {
    const int p = start + i;
    const int s = cs_src[p];
    const int eid = cs_eid[p];
    const float* ap = attr + (size_t)eid * 16;
    const float4 a0 = *(const float4*)(ap);
    const float4 a1 = *(const float4*)(ap + 4);
    const float4 a2 = *(const float4*)(ap + 8);
    const float4 a3 = *(const float4*)(ap + 12);
    const float av[16] = {a0.x, a0.y, a0.z, a0.w, a1.x, a1.y, a1.z, a1.w,
                          a2.x, a2.y, a2.z, a2.w, a3.x, a3.y, a3.z, a3.w};
    float4 ev = bev;
    #pragma unroll
    for (int k = 0; k < 16; ++k) {
      const float4 w = *(const float4*)&we_lds[k * 128 + c0];
      ev.x = fmaf(av[k], w.x, ev.x);
      ev.y = fmaf(av[k], w.y, ev.y);
      ev.z = fmaf(av[k], w.z, ev.z);
      ev.w = fmaf(av[k], w.w, ev.w);
    }
    const float4 xv = *(const float4*)(x + (size_t)s * H_D + c0);
    acc.x += fmaxf(xv.x + fmaxf(ev.x, 0.f), 0.f);
    acc.y += fmaxf(xv.y + fmaxf(ev.y, 0.f), 0.f);
    acc.z += fmaxf(xv.z + fmaxf(ev.z, 0.f), 0.f);
    acc.w += fmaxf(xv.w + fmaxf(ev.w, 0.f), 0.f);
  }
  *(float4*)(agg + (size_t)v * H_D + c0) = acc;
}

// ---- head: logit = relu([x | x_inp]@Wm1+bm1)@Wm2+bm2, K=192 ----------------
__global__ __launch_bounds__(256, 4) void k_head(
    const float* __restrict__ x, const float* __restrict__ x_inp,
    const float* __restrict__ Wm1, const float* __restrict__ bm1,
    const float* __restrict__ Wm2, const float* __restrict__ bm2,
    float* __restrict__ logit)
{
  __shared__ float w_lds[32 * WSTRIDE];
  __shared__ float in_ldsT[32 * ISTRIDE];
  const int t = threadIdx.x;
  const int row0 = blockIdx.x * 64;
  const int r0 = (t >> 4) << 2;
  const int c0 = (t & 15) * 8;
  const int swc0 = SWZ(c0), swc1 = SWZ(c0 + 4);
  const int rs = t >> 2, qs = t & 3;
  const int kw = t >> 3, cw = (t & 7) * 16;
  float acc[4][8] = {};
  for (int kc = 0; kc < 6; ++kc) {
    const int k0 = kc * 32;
    const float* src = (k0 < 128)
        ? x + (size_t)(row0 + rs) * H_D + k0
        : x_inp + (size_t)(row0 + rs) * FV_D + (k0 - 128);
    const float4 v0 = *(const float4*)(src + qs * 4);
    const float4 v1 = *(const float4*)(src + 16 + qs * 4);
    const float* wp = Wm1 + (size_t)(k0 + kw) * H_D + cw;
    float4 wv[4];
    #pragma unroll
    for (int u = 0; u < 4; ++u) wv[u] = *(const float4*)(wp + u * 4);
    __syncthreads();
    #pragma unroll
    for (int u = 0; u < 4; ++u)
      *(float4*)&w_lds[kw * WSTRIDE + SWZ(cw + u * 4)] = wv[u];
    stage_in4(in_ldsT, qs * 4, rs, v0);
    stage_in4(in_ldsT, qs * 4 + 16, rs, v1);
    __syncthreads();
    mma32(in_ldsT, w_lds, r0, swc0, swc1, acc);
  }
  const float4 b0v = *(const float4*)(bm1 + c0);
  const float4 b1v = *(const float4*)(bm1 + c0 + 4);
  const float4 w0v = *(const float4*)(Wm2 + c0);
  const float4 w1v = *(const float4*)(Wm2 + c0 + 4);
  const float bv[8] = {b0v.x, b0v.y, b0v.z, b0v.w, b1v.x, b1v.y, b1v.z, b1v.w};
  const float wv[8] = {w0v.x, w0v.y, w0v.z, w0v.w, w1v.x, w1v.y, w1v.z, w1v.w};
  float s[4];
  #pragma unroll
  for (int i = 0; i < 4; ++i) {
    float v = 0.f;
    #pragma unroll
    for (int j = 0; j < 8; ++j)
      v += fmaxf(acc[i][j] + bv[j], 0.f) * wv[j];
    s[i] = v;
  }
  #pragma unroll
  for (int off = 1; off < 16; off <<= 1) {
    #pragma unroll
    for (int i = 0; i < 4; ++i) s[i] += __shfl_xor(s[i], off);
  }
  if ((t & 15) == 0) {
    const float bb = bm2[0];
    #pragma unroll
    for (int i = 0; i < 4; ++i) logit[row0 + r0 + i] = s[i] + bb;
  }
}

// ---- segment softmax over sorted n2g: one wave per graph -------------------
__device__ __forceinline__ int lower_bound_i(const int* __restrict__ a, int n, int v)
{
  int lo = 0, hi = n;
  while (lo < hi) {
    const int mid = (lo + hi) >> 1;
    if (a[mid] < v) lo = mid + 1; else hi = mid;
  }
  return lo;
}

__global__ __launch_bounds__(256, 4) void k_softmax(
    const float* __restrict__ logit, const int* __restrict__ n2g,
    float* __restrict__ P)
{
  const int lane = threadIdx.x & 63;
  const int g = blockIdx.x * 4 + (threadIdx.x >> 6);
  const int s = lower_bound_i(n2g, V_N, g);
  const int e = lower_bound_i(n2g, V_N, g + 1);
  float m = -3.4e38f;
  for (int i = s + lane; i < e; i += 64) m = fmaxf(m, logit[i]);
  #pragma unroll
  for (int off = 32; off; off >>= 1) m = fmaxf(m, __shfl_xor(m, off));
  float sum = 0.f;
  for (int i = s + lane; i < e; i += 64) sum += __expf(logit[i] - m);
  #pragma unroll
  for (int off = 32; off; off >>= 1) sum += __shfl_xor(sum, off);
  const float inv = 1.f / sum;
  for (int i = s + lane; i < e; i += 64) P[i] = __expf(logit[i] - m) * inv;
}

extern "C" void kernel_launch(void* const* d_in, const int* in_sizes, int n_in,
                              void* d_out, int out_size, void* d_ws, size_t ws_size,
                              hipStream_t stream)
{
  const float* x_inp  = (const float*)d_in[0];
  const int*   eidx   = (const int*)  d_in[1];
  const float* attr   = (const float*)d_in[2];
  const float* x_upd  = (const float*)d_in[3];
  const float* Zc     = (const float*)d_in[4];
  const float* Zb     = (const float*)d_in[5];
  const int*   n2g    = (const int*)  d_in[6];
  const float* W_emb  = (const float*)d_in[7];
  const float* b_emb  = (const float*)d_in[8];
  const float* W_edge = (const float*)d_in[9];
  const float* b_edge = (const float*)d_in[10];
  const float* W1     = (const float*)d_in[11];
  const float* b1     = (const float*)d_in[12];
  const float* W2     = (const float*)d_in[13];
  const float* b2     = (const float*)d_in[14];
  const float* W_m1   = (const float*)d_in[15];
  const float* b_m1   = (const float*)d_in[16];
  const float* W_m2   = (const float*)d_in[17];
  const float* b_m2   = (const float*)d_in[18];

  float* ws     = (float*)d_ws;
  float* x      = ws;                          // V*H floats
  float* agg    = x + (size_t)V_N * H_D;       // V*H floats (also reused as h)
  int*   deg    = (int*)(agg + (size_t)V_N * H_D);  // V ints
  int*   rp     = deg + V_N;                   // V ints (row start)
  int*   cursor = rp + V_N;                    // V ints; dead after k_fill
  int*   cs_src = cursor + V_N;                // E ints
  int*   cs_eid = cs_src + E_N;                // E ints
  int*   bsum   = cs_eid + E_N;                // 256 ints
  float* logit  = (float*)cursor;              // V floats, aliases dead cursor

  // ---- CSR by dst (edge_index is call-invariant across layers) ----
  hipMemsetAsync(deg, 0, (size_t)V_N * sizeof(int), stream);
  k_hist<<<E_N / 256, 256, 0, stream>>>(eidx, deg);
  k_scan_local<<<256, 256, 0, stream>>>(deg, rp, bsum);
  k_scan_bsum<<<1, 256, 0, stream>>>(bsum);
  k_scan_add<<<256, 256, 0, stream>>>(rp, cursor, bsum);
  k_fill<<<E_N / 256, 256, 0, stream>>>(eidx, cursor, cs_src, cs_eid);

  // ---- model ----
  k_embed<<<V_N / 64, 256, 0, stream>>>(x_upd, Zc, Zb, n2g, W_emb, b_emb, x);
  for (int l = 0; l < 4; ++l) {
    k_gather<<<V_N / 8, 256, 0, stream>>>(x, attr, rp, deg, cs_src, cs_eid,
                                          W_edge, b_edge, agg);
    k_gemm_xa<<<V_N / 64, 256, 0, stream>>>(x, agg, W1 + (size_t)l * H_D * H_D,
                                            b1 + (size_t)l * H_D, agg /* h */);
    k_gemm_res<<<V_N / 64, 256, 0, stream>>>(agg /* h */, W2 + (size_t)l * H_D * H_D,
                                             b2 + (size_t)l * H_D, x);
  }
  k_head<<<V_N / 64, 256, 0, stream>>>(x, x_inp, W_m1, b_m1, W_m2, b_m2, logit);
  k_softmax<<<N_G / 4, 256, 0, stream>>>(logit, n2g, (float*)d_out);
}